// Round 3
// baseline (1746.930 us; speedup 1.0000x reference)
//
#include <hip/hip_runtime.h>

// 3D Jacobi (6-neighbor), 20 sweeps, zero-Dirichlet.
// step_first (padded pre) + 9x fused double-sweeps (2.5D blocking) + 1 single sweep.

#define NP 258
#define NI 256
#define HHC ((1.0f / 257.0f) * (1.0f / 257.0f))
#define SIXTH (1.0f / 6.0f)

#define TX 32
#define TY 32
#define CZ 32

// First sweep: reads padded pre (random halo included). pre -> interior layout.
__global__ void step_first(const float* __restrict__ pre,
                           const float* __restrict__ f,
                           float* __restrict__ out) {
    const int x = threadIdx.x;
    const int y = blockIdx.y;
    const int z = blockIdx.z;
    const int sP = NP * NP;
    const int c  = (z + 1) * sP + (y + 1) * NP + (x + 1);
    const float nb = pre[c - sP] + pre[c + sP]
                   + pre[c - NP] + pre[c + NP]
                   + pre[c - 1]  + pre[c + 1];
    out[(z * NI + y) * NI + x] = (nb + HHC * f[c]) * SIXTH;
}

// Single sweep, float4, f read direct from padded layout.
__global__ void step_inner_v(const float4* __restrict__ u4,
                             const float* __restrict__ f,
                             float4* __restrict__ out4) {
    const int tx = threadIdx.x;                    // 0..63
    const int y  = blockIdx.y * 4 + threadIdx.y;
    const int z  = blockIdx.z;
    const int rowq   = NI / 4;
    const int planeq = NI * rowq;
    const int r = z * planeq + y * rowq + tx;

    const float4 v = u4[r];
    float left  = __shfl_up(v.w, 1);
    float right = __shfl_down(v.x, 1);
    if (tx == 0)  left  = 0.0f;
    if (tx == 63) right = 0.0f;

    float4 nb;
    nb.x = left + v.y;
    nb.y = v.x  + v.z;
    nb.z = v.y  + v.w;
    nb.w = v.z  + right;

    if (y > 0)      { float4 b = u4[r - rowq];   nb.x += b.x; nb.y += b.y; nb.z += b.z; nb.w += b.w; }
    if (y < NI - 1) { float4 b = u4[r + rowq];   nb.x += b.x; nb.y += b.y; nb.z += b.z; nb.w += b.w; }
    if (z > 0)      { float4 b = u4[r - planeq]; nb.x += b.x; nb.y += b.y; nb.z += b.z; nb.w += b.w; }
    if (z < NI - 1) { float4 b = u4[r + planeq]; nb.x += b.x; nb.y += b.y; nb.z += b.z; nb.w += b.w; }

    const int fc = (z + 1) * NP * NP + (y + 1) * NP + (4 * tx + 1);
    nb.x += HHC * f[fc];
    nb.y += HHC * f[fc + 1];
    nb.z += HHC * f[fc + 2];
    nb.w += HHC * f[fc + 3];

    float4 o;
    o.x = nb.x * SIXTH; o.y = nb.y * SIXTH; o.z = nb.z * SIXTH; o.w = nb.w * SIXTH;
    out4[r] = o;
}

// Fused double sweep: out = J(J(u)), 2.5D z-marching with LDS plane rings.
__global__ __launch_bounds__(256, 2)
void step_fused2(const float* __restrict__ u,
                 const float* __restrict__ f,
                 float* __restrict__ out) {
    __shared__ float su[3][36 * 36];   // u planes, halo 2
    __shared__ float sw[3][34 * 34];   // intermediate planes, halo 1

    const int tid = threadIdx.x;
    const int x0 = blockIdx.x * TX;
    const int y0 = blockIdx.y * TY;
    const int z0 = blockIdx.z * CZ;

    for (int t = z0 - 4; t < z0 + CZ; ++t) {
        // ---- Phase L: load u plane p = t+2 into ring slot ----
        {
            const int p = t + 2;
            float* dst = su[(p + 6) % 3];
            const bool pz = (p >= 0 && p < NI);
            for (int i = tid; i < 36 * 36; i += 256) {
                const int ly = i / 36, lx = i - 36 * ly;
                const int gy = y0 - 2 + ly, gx = x0 - 2 + lx;
                float v = 0.0f;
                if (pz && gy >= 0 && gy < NI && gx >= 0 && gx < NI)
                    v = u[(p * NI + gy) * NI + gx];
                dst[i] = v;
            }
        }
        __syncthreads();
        // ---- Phase W: compute intermediate plane p = t+1 ----
        if (t + 1 >= z0 - 1) {
            const int p = t + 1;
            const float* cc = su[(p + 6) % 3];
            const float* zm = su[(p + 5) % 3];
            const float* zp = su[(p + 7) % 3];
            float* w = sw[(p + 6) % 3];
            const bool pz = (p >= 0 && p < NI);
            for (int i = tid; i < 34 * 34; i += 256) {
                const int wy = i / 34, wx = i - 34 * wy;
                const int gy = y0 - 1 + wy, gx = x0 - 1 + wx;
                float v = 0.0f;
                if (pz && gy >= 0 && gy < NI && gx >= 0 && gx < NI) {
                    const int li = (wy + 1) * 36 + (wx + 1);
                    const float nb = cc[li - 1] + cc[li + 1]
                                   + cc[li - 36] + cc[li + 36]
                                   + zm[li] + zp[li];
                    v = (nb + HHC * f[((p + 1) * NP + (gy + 1)) * NP + (gx + 1)]) * SIXTH;
                }
                w[i] = v;
            }
        }
        __syncthreads();
        // ---- Phase O: compute+store out plane t ----
        if (t >= z0) {
            const float* cc = sw[(t + 6) % 3];
            const float* zm = sw[(t + 5) % 3];
            const float* zp = sw[(t + 7) % 3];
            for (int i = tid; i < 32 * 32; i += 256) {
                const int oy = i >> 5, ox = i & 31;
                const int gy = y0 + oy, gx = x0 + ox;
                const int li = (oy + 1) * 34 + (ox + 1);
                const float nb = cc[li - 1] + cc[li + 1]
                               + cc[li - 34] + cc[li + 34]
                               + zm[li] + zp[li];
                const float v = (nb + HHC * f[((t + 1) * NP + (gy + 1)) * NP + (gx + 1)]) * SIXTH;
                out[(t * NI + gy) * NI + gx] = v;
            }
        }
        __syncthreads();
    }
}

extern "C" void kernel_launch(void* const* d_in, const int* in_sizes, int n_in,
                              void* d_out, int out_size, void* d_ws, size_t ws_size,
                              hipStream_t stream) {
    const float* pre = (const float*)d_in[0];
    const float* f   = (const float*)d_in[1];
    float* out = (float*)d_out;
    float* buf = (float*)d_ws;      // 64 MiB ping-pong

    // 20 sweeps total: step_first (1) + 9 fused (18) + 1 single.
    // step_first -> out; then 10 ping-pong launches end back in out.
    step_first<<<dim3(1, NI, NI), dim3(NI, 1, 1), 0, stream>>>(pre, f, out);

    float* cur = out;
    float* nxt = buf;
    dim3 fg(NI / TX, NI / TY, NI / CZ);    // 8x8x8 = 512 blocks
    for (int i = 0; i < 9; ++i) {
        step_fused2<<<fg, dim3(256, 1, 1), 0, stream>>>(cur, f, nxt);
        float* tmp = cur; cur = nxt; nxt = tmp;
    }
    // cur == buf after 9 swaps; final single sweep buf -> out.
    step_inner_v<<<dim3(1, NI / 4, NI), dim3(64, 4, 1), 0, stream>>>(
        (const float4*)cur, f, (float4*)out);
}

// Round 4
// 910.489 us; speedup vs baseline: 1.9187x; 1.9187x over previous
//
#include <hip/hip_runtime.h>

// 3D Jacobi (6-neighbor), 20 sweeps, zero-Dirichlet.
// step_first + 9x fused double-sweeps (2.5D z-march, ring-4/ring-3, 2 barriers/iter) + 1 single sweep.

#define NP 258
#define NI 256
#define HHC ((1.0f / 257.0f) * (1.0f / 257.0f))
#define SIXTH (1.0f / 6.0f)

#define TX 32
#define TY 32
#define CZ 16

// First sweep: reads padded pre (random halo included). pre -> interior layout.
__global__ void step_first(const float* __restrict__ pre,
                           const float* __restrict__ f,
                           float* __restrict__ out) {
    const int x = threadIdx.x;
    const int y = blockIdx.y;
    const int z = blockIdx.z;
    const int sP = NP * NP;
    const int c  = (z + 1) * sP + (y + 1) * NP + (x + 1);
    const float nb = pre[c - sP] + pre[c + sP]
                   + pre[c - NP] + pre[c + NP]
                   + pre[c - 1]  + pre[c + 1];
    out[(z * NI + y) * NI + x] = (nb + HHC * f[c]) * SIXTH;
}

// Single sweep, float4.
__global__ void step_inner_v(const float4* __restrict__ u4,
                             const float* __restrict__ f,
                             float4* __restrict__ out4) {
    const int tx = threadIdx.x;                    // 0..63
    const int y  = blockIdx.y * 4 + threadIdx.y;
    const int z  = blockIdx.z;
    const int rowq   = NI / 4;
    const int planeq = NI * rowq;
    const int r = z * planeq + y * rowq + tx;

    const float4 v = u4[r];
    float left  = __shfl_up(v.w, 1);
    float right = __shfl_down(v.x, 1);
    if (tx == 0)  left  = 0.0f;
    if (tx == 63) right = 0.0f;

    float4 nb;
    nb.x = left + v.y;
    nb.y = v.x  + v.z;
    nb.z = v.y  + v.w;
    nb.w = v.z  + right;

    if (y > 0)      { float4 b = u4[r - rowq];   nb.x += b.x; nb.y += b.y; nb.z += b.z; nb.w += b.w; }
    if (y < NI - 1) { float4 b = u4[r + rowq];   nb.x += b.x; nb.y += b.y; nb.z += b.z; nb.w += b.w; }
    if (z > 0)      { float4 b = u4[r - planeq]; nb.x += b.x; nb.y += b.y; nb.z += b.z; nb.w += b.w; }
    if (z < NI - 1) { float4 b = u4[r + planeq]; nb.x += b.x; nb.y += b.y; nb.z += b.z; nb.w += b.w; }

    const int fc = (z + 1) * NP * NP + (y + 1) * NP + (4 * tx + 1);
    nb.x += HHC * f[fc];
    nb.y += HHC * f[fc + 1];
    nb.z += HHC * f[fc + 2];
    nb.w += HHC * f[fc + 3];

    float4 o;
    o.x = nb.x * SIXTH; o.y = nb.y * SIXTH; o.z = nb.z * SIXTH; o.w = nb.w * SIXTH;
    out4[r] = o;
}

// Fused double sweep: out = J(J(u)).
// Per z-iter: L loads su[t+3] (ring-4, disjoint from W's reads -> no barrier),
// W computes sw[t+1] (ring-3), barrier, O stores out[t], barrier.
__global__ __launch_bounds__(512, 8)
void step_fused2(const float* __restrict__ u,
                 const float* __restrict__ f,
                 float* __restrict__ out) {
    __shared__ float su[4][36 * 36];   // u planes, halo 2, ring-4
    __shared__ float sw[3][34 * 34];   // intermediate planes, halo 1, ring-3

    const int tid = threadIdx.x;
    const int x0 = blockIdx.x * TX;
    const int y0 = blockIdx.y * TY;
    const int z0 = blockIdx.z * CZ;
    const int zend = z0 + CZ;

    for (int t = z0 - 5; t < zend; ++t) {
        // ---- L: load su plane t+3 (used by W at iters t+1..t+3) ----
        if (t <= zend - 2) {
            const int pl = t + 3;
            float* dst = su[pl & 3];
            const bool pz = (pl >= 0 && pl < NI);
            for (int i = tid; i < 36 * 36; i += 512) {
                const int ly = i / 36, lx = i - 36 * ly;
                const int gy = y0 - 2 + ly, gx = x0 - 2 + lx;
                float v = 0.0f;
                if (pz && gy >= 0 && gy < NI && gx >= 0 && gx < NI)
                    v = u[(pl * NI + gy) * NI + gx];
                dst[i] = v;
            }
        }
        // ---- W: compute sw plane t+1 from su[t..t+2] (no barrier vs L) ----
        if (t >= z0 - 2) {
            const int pw = t + 1;
            const float* zm = su[(pw - 1) & 3];
            const float* cc = su[pw & 3];
            const float* zp = su[(pw + 1) & 3];
            float* w = sw[(pw + 3) % 3];
            const bool pz = (pw >= 0 && pw < NI);
            for (int i = tid; i < 34 * 34; i += 512) {
                const int wy = i / 34, wx = i - 34 * wy;
                const int gy = y0 - 1 + wy, gx = x0 - 1 + wx;
                float v = 0.0f;
                if (pz && gy >= 0 && gy < NI && gx >= 0 && gx < NI) {
                    const int li = (wy + 1) * 36 + (wx + 1);
                    v = (cc[li - 1] + cc[li + 1] + cc[li - 36] + cc[li + 36]
                         + zm[li] + zp[li]
                         + HHC * f[((pw + 1) * NP + (gy + 1)) * NP + (gx + 1)]) * SIXTH;
                }
                w[i] = v;
            }
        }
        __syncthreads();
        // ---- O: out plane t from sw[t-1..t+1] ----
        if (t >= z0) {
            const float* zm = sw[(t + 2) % 3];
            const float* cc = sw[t % 3];
            const float* zp = sw[(t + 1) % 3];
            for (int i = tid; i < 32 * 32; i += 512) {
                const int oy = i >> 5, ox = i & 31;
                const int gy = y0 + oy, gx = x0 + ox;
                const int li = (oy + 1) * 34 + (ox + 1);
                const float v = (cc[li - 1] + cc[li + 1] + cc[li - 34] + cc[li + 34]
                               + zm[li] + zp[li]
                               + HHC * f[((t + 1) * NP + (gy + 1)) * NP + (gx + 1)]) * SIXTH;
                out[(t * NI + gy) * NI + gx] = v;
            }
        }
        __syncthreads();
    }
}

extern "C" void kernel_launch(void* const* d_in, const int* in_sizes, int n_in,
                              void* d_out, int out_size, void* d_ws, size_t ws_size,
                              hipStream_t stream) {
    const float* pre = (const float*)d_in[0];
    const float* f   = (const float*)d_in[1];
    float* out = (float*)d_out;
    float* buf = (float*)d_ws;      // 64 MiB ping-pong

    // 20 sweeps: step_first (1) + 9 fused (18) + 1 single.
    step_first<<<dim3(1, NI, NI), dim3(NI, 1, 1), 0, stream>>>(pre, f, out);

    float* cur = out;
    float* nxt = buf;
    dim3 fg(NI / TX, NI / TY, NI / CZ);    // 8x8x16 = 1024 blocks
    for (int i = 0; i < 9; ++i) {
        step_fused2<<<fg, dim3(512, 1, 1), 0, stream>>>(cur, f, nxt);
        float* tmp = cur; cur = nxt; nxt = tmp;
    }
    // cur == buf after 9 swaps; final single sweep buf -> out.
    step_inner_v<<<dim3(1, NI / 4, NI), dim3(64, 4, 1), 0, stream>>>(
        (const float4*)cur, f, (float4*)out);
}

// Round 5
// 815.820 us; speedup vs baseline: 2.1413x; 1.1160x over previous
//
#include <hip/hip_runtime.h>

// 3D Jacobi (6-neighbor), 20 sweeps, zero-Dirichlet.
// step_first_v (padded pre -> out + g=h^2*f) + 9x fused double-sweeps (float4 2.5D
// pipeline, ring-4/ring-3, 2 barriers/iter) + 1 single float4 sweep.

#define NP 258
#define NI 256
#define HHC ((1.0f / 257.0f) * (1.0f / 257.0f))
#define SIXTH (1.0f / 6.0f)

#define TX 32
#define TY 32
#define CZ 16

#define SU_ROWS 36   // u rows [y0-2, y0+34)
#define SU_Q 10      // f4 per su row, covering [x0-4, x0+36)
#define SW_ROWS 34   // w rows [y0-1, y0+33)
#define SW_Q 10      // f4 per sw row, covering [x0-4, x0+36)

__device__ __forceinline__ float4 ld4u(const float* p) {   // 4B-aligned f4 load
    float4 v; __builtin_memcpy(&v, p, sizeof(float4)); return v;
}

// First sweep, vectorized: reads padded pre (incl. its random halo), writes
// out (interior layout) and g = h^2 * f (contiguous interior layout).
__global__ void step_first_v(const float* __restrict__ pre,
                             const float* __restrict__ f,
                             float* __restrict__ out,
                             float* __restrict__ g) {
    const int tx = threadIdx.x;                  // 0..63
    const int y  = blockIdx.y * 4 + threadIdx.y; // 0..255
    const int z  = blockIdx.z;
    const int gx0 = 4 * tx;
    const size_t sP = (size_t)NP * NP;
    const size_t prow = (size_t)(z + 1) * sP + (size_t)(y + 1) * NP + 1;

    const float4 C  = ld4u(&pre[prow + gx0]);
    const float4 up = ld4u(&pre[prow - NP + gx0]);
    const float4 dn = ld4u(&pre[prow + NP + gx0]);
    const float4 zm = ld4u(&pre[prow - sP + gx0]);
    const float4 zp = ld4u(&pre[prow + sP + gx0]);
    float4 fv = ld4u(&f[prow + gx0]);
    fv.x *= HHC; fv.y *= HHC; fv.z *= HHC; fv.w *= HHC;

    float lft = __shfl_up(C.w, 1);
    if (tx == 0)  lft = pre[prow + gx0 - 1];     // padded halo (random) on purpose
    float rgt = __shfl_down(C.x, 1);
    if (tx == 63) rgt = pre[prow + gx0 + 4];

    float4 o;
    o.x = (lft + C.y + up.x + dn.x + zm.x + zp.x + fv.x) * SIXTH;
    o.y = (C.x + C.z + up.y + dn.y + zm.y + zp.y + fv.y) * SIXTH;
    o.z = (C.y + C.w + up.z + dn.z + zm.z + zp.z + fv.z) * SIXTH;
    o.w = (C.z + rgt + up.w + dn.w + zm.w + zp.w + fv.w) * SIXTH;

    const size_t oi = ((size_t)z * NI + y) * NI + gx0;
    *reinterpret_cast<float4*>(&out[oi]) = o;
    *reinterpret_cast<float4*>(&g[oi])  = fv;
}

// Final single sweep, float4, using g.
__global__ void step_last_v(const float4* __restrict__ u4,
                            const float4* __restrict__ g4,
                            float4* __restrict__ out4) {
    const int tx = threadIdx.x;                    // 0..63
    const int y  = blockIdx.y * 4 + threadIdx.y;
    const int z  = blockIdx.z;
    const int rowq   = NI / 4;
    const int planeq = NI * rowq;
    const int r = z * planeq + y * rowq + tx;

    const float4 v = u4[r];
    float left  = __shfl_up(v.w, 1);
    float right = __shfl_down(v.x, 1);
    if (tx == 0)  left  = 0.0f;
    if (tx == 63) right = 0.0f;

    float4 nb;
    nb.x = left + v.y;
    nb.y = v.x  + v.z;
    nb.z = v.y  + v.w;
    nb.w = v.z  + right;

    if (y > 0)      { float4 b = u4[r - rowq];   nb.x += b.x; nb.y += b.y; nb.z += b.z; nb.w += b.w; }
    if (y < NI - 1) { float4 b = u4[r + rowq];   nb.x += b.x; nb.y += b.y; nb.z += b.z; nb.w += b.w; }
    if (z > 0)      { float4 b = u4[r - planeq]; nb.x += b.x; nb.y += b.y; nb.z += b.z; nb.w += b.w; }
    if (z < NI - 1) { float4 b = u4[r + planeq]; nb.x += b.x; nb.y += b.y; nb.z += b.z; nb.w += b.w; }

    const float4 gv = g4[r];
    float4 o;
    o.x = (nb.x + gv.x) * SIXTH;
    o.y = (nb.y + gv.y) * SIXTH;
    o.z = (nb.z + gv.z) * SIXTH;
    o.w = (nb.w + gv.w) * SIXTH;
    out4[r] = o;
}

// Fused double sweep out = J(J(u)), all-float4 2.5D pipeline.
// Per iter t: L loads su[t+3] (ring-4, disjoint from W reads -> no barrier),
// W computes sw[t+1] from su[t..t+2] + g, barrier, O stores out[t] from
// sw[t-1..t+1] + g, barrier.
__global__ __launch_bounds__(512, 8)
void step_fused2v(const float* __restrict__ u,
                  const float* __restrict__ g,
                  float* __restrict__ out) {
    __shared__ float4 su[4][SU_ROWS][SU_Q];
    __shared__ float4 sw[3][SW_ROWS][SW_Q];

    const int tid = threadIdx.x;
    const int x0 = blockIdx.x * TX;
    const int y0 = blockIdx.y * TY;
    const int z0 = blockIdx.z * CZ;

    // ---- loop-invariant per-thread mappings ----
    // L: 360 threads, one f4 chunk each
    const int lr = tid / SU_Q;
    const int lc = tid - lr * SU_Q;
    const bool lact = tid < SU_ROWS * SU_Q;
    const int lgy  = y0 - 2 + lr;
    const int lgx0 = x0 - 4 + 4 * lc;
    const bool lxy = lact && lgy >= 0 && lgy < NI && lgx0 >= 0 && lgx0 < NI;

    // W: 340 threads
    const int wr = tid / SW_Q;
    const int wc = tid - wr * SW_Q;
    const bool wact = tid < SW_ROWS * SW_Q;
    const int wgy  = y0 - 1 + wr;
    const int wgx0 = x0 - 4 + 4 * wc;
    const bool wxy = wact && wgy >= 0 && wgy < NI && wgx0 >= 0 && wgx0 < NI;
    const int wcm = (wc > 0) ? wc - 1 : 0;          // clamped: garbage lanes unused
    const int wcp = (wc < SW_Q - 1) ? wc + 1 : SW_Q - 1;

    // O: 256 threads
    const int orr = tid >> 3;
    const int oc  = tid & 7;
    const bool oact = tid < 256;
    const int ogy  = y0 + orr;
    const int ogx0 = x0 + 4 * oc;

    for (int t = z0 - 5; t < z0 + CZ; ++t) {
        // ---- L: load u plane pl = t+3 into ring slot (pl & 3) ----
        if (lact && t <= z0 + CZ - 2) {
            const int pl = t + 3;
            float4 v = make_float4(0.f, 0.f, 0.f, 0.f);
            if (lxy && pl >= 0 && pl < NI)
                v = *reinterpret_cast<const float4*>(
                        &u[((size_t)pl * NI + lgy) * NI + lgx0]);
            su[pl & 3][lr][lc] = v;
        }
        // ---- W: compute sw plane pw = t+1 (reads su t..t+2; no barrier vs L) ----
        if (wact && t >= z0 - 2) {
            const int pw = t + 1;
            float4 wv = make_float4(0.f, 0.f, 0.f, 0.f);
            if (wxy && pw >= 0 && pw < NI) {
                const int s0 = pw & 3, sm = (pw - 1) & 3, sp = (pw + 1) & 3;
                const float4 cc = su[s0][wr + 1][wc];
                const float4 cp = su[s0][wr + 1][wcm];
                const float4 cn = su[s0][wr + 1][wcp];
                const float4 uy = su[s0][wr][wc];
                const float4 dy = su[s0][wr + 2][wc];
                const float4 zm = su[sm][wr + 1][wc];
                const float4 zp = su[sp][wr + 1][wc];
                const float4 gv = *reinterpret_cast<const float4*>(
                        &g[((size_t)pw * NI + wgy) * NI + wgx0]);
                wv.x = (cp.w + cc.y + uy.x + dy.x + zm.x + zp.x + gv.x) * SIXTH;
                wv.y = (cc.x + cc.z + uy.y + dy.y + zm.y + zp.y + gv.y) * SIXTH;
                wv.z = (cc.y + cc.w + uy.z + dy.z + zm.z + zp.z + gv.z) * SIXTH;
                wv.w = (cc.z + cn.x + uy.w + dy.w + zm.w + zp.w + gv.w) * SIXTH;
            }
            sw[(pw + 3) % 3][wr][wc] = wv;
        }
        __syncthreads();
        // ---- O: out plane t from sw[t-1..t+1] ----
        if (oact && t >= z0) {
            const int s0 = (t + 3) % 3, sm = (t + 2) % 3, sp = (t + 4) % 3;
            const float4 cc = sw[s0][orr + 1][oc + 1];
            const float4 cp = sw[s0][orr + 1][oc];
            const float4 cn = sw[s0][orr + 1][oc + 2];
            const float4 uy = sw[s0][orr][oc + 1];
            const float4 dy = sw[s0][orr + 2][oc + 1];
            const float4 zm = sw[sm][orr + 1][oc + 1];
            const float4 zp = sw[sp][orr + 1][oc + 1];
            const size_t oi = ((size_t)t * NI + ogy) * NI + ogx0;
            const float4 gv = *reinterpret_cast<const float4*>(&g[oi]);
            float4 ov;
            ov.x = (cp.w + cc.y + uy.x + dy.x + zm.x + zp.x + gv.x) * SIXTH;
            ov.y = (cc.x + cc.z + uy.y + dy.y + zm.y + zp.y + gv.y) * SIXTH;
            ov.z = (cc.y + cc.w + uy.z + dy.z + zm.z + zp.z + gv.z) * SIXTH;
            ov.w = (cc.z + cn.x + uy.w + dy.w + zm.w + zp.w + gv.w) * SIXTH;
            *reinterpret_cast<float4*>(&out[oi]) = ov;
        }
        __syncthreads();
    }
}

extern "C" void kernel_launch(void* const* d_in, const int* in_sizes, int n_in,
                              void* d_out, int out_size, void* d_ws, size_t ws_size,
                              hipStream_t stream) {
    const float* pre = (const float*)d_in[0];
    const float* f   = (const float*)d_in[1];
    float* out = (float*)d_out;
    float* buf = (float*)d_ws;                          // 64 MiB ping-pong
    const size_t nInt = (size_t)NI * NI * NI;
    float* g = buf + nInt;                              // 64 MiB, g = h^2*f (ws >= 128 MiB, verified R1)

    // 20 sweeps: step_first (1) + 9 fused (18) + 1 single.
    step_first_v<<<dim3(1, NI / 4, NI), dim3(64, 4, 1), 0, stream>>>(pre, f, out, g);

    float* cur = out;
    float* nxt = buf;
    dim3 fg(NI / TX, NI / TY, NI / CZ);                 // 8x8x16 = 1024 blocks
    for (int i = 0; i < 9; ++i) {
        step_fused2v<<<fg, dim3(512, 1, 1), 0, stream>>>(cur, g, nxt);
        float* tmp = cur; cur = nxt; nxt = tmp;
    }
    // cur == buf after 9 swaps; final single sweep buf -> out.
    step_last_v<<<dim3(1, NI / 4, NI), dim3(64, 4, 1), 0, stream>>>(
        (const float4*)cur, (const float4*)g, (float4*)out);
}

// Round 6
// 451.074 us; speedup vs baseline: 3.8728x; 1.8086x over previous
//
#include <hip/hip_runtime.h>

// 3D Jacobi (6-neighbor), 20 sweeps, zero-Dirichlet.
// step_first_v (padded pre -> out + g=h^2*f) + 9x fused double-sweeps
// (float4 2.5D pipeline, ring-3/ring-3, 2 barriers/iter, register-prefetched
// globals, padded LDS rows, XCD-contiguous tile remap) + 1 single float4 sweep.

#define NP 258
#define NI 256
#define HHC ((1.0f / 257.0f) * (1.0f / 257.0f))
#define SIXTH (1.0f / 6.0f)

#define TX 32
#define TY 32
#define CZ 16

#define SU_ROWS 36   // u rows [y0-2, y0+34)
#define SU_Q 10      // useful f4 per su row: [x0-4, x0+36)
#define SU_P 11      // padded row stride (f4) -> 44 words % 32 banks = 12
#define SW_ROWS 34   // w rows [y0-1, y0+33)
#define SW_Q 10
#define SW_P 11

__device__ __forceinline__ float4 ld4u(const float* p) {   // 4B-aligned f4 load
    float4 v; __builtin_memcpy(&v, p, sizeof(float4)); return v;
}
__device__ __forceinline__ float4 zero4() { return make_float4(0.f, 0.f, 0.f, 0.f); }

// First sweep, vectorized: reads padded pre (incl. its random halo), writes
// out (interior layout) and g = h^2 * f (contiguous interior layout).
__global__ void step_first_v(const float* __restrict__ pre,
                             const float* __restrict__ f,
                             float* __restrict__ out,
                             float* __restrict__ g) {
    const int tx = threadIdx.x;                  // 0..63
    const int y  = blockIdx.y * 4 + threadIdx.y; // 0..255
    const int z  = blockIdx.z;
    const int gx0 = 4 * tx;
    const size_t sP = (size_t)NP * NP;
    const size_t prow = (size_t)(z + 1) * sP + (size_t)(y + 1) * NP + 1;

    const float4 C  = ld4u(&pre[prow + gx0]);
    const float4 up = ld4u(&pre[prow - NP + gx0]);
    const float4 dn = ld4u(&pre[prow + NP + gx0]);
    const float4 zm = ld4u(&pre[prow - sP + gx0]);
    const float4 zp = ld4u(&pre[prow + sP + gx0]);
    float4 fv = ld4u(&f[prow + gx0]);
    fv.x *= HHC; fv.y *= HHC; fv.z *= HHC; fv.w *= HHC;

    float lft = __shfl_up(C.w, 1);
    if (tx == 0)  lft = pre[prow + gx0 - 1];     // padded halo (random) on purpose
    float rgt = __shfl_down(C.x, 1);
    if (tx == 63) rgt = pre[prow + gx0 + 4];

    float4 o;
    o.x = (lft + C.y + up.x + dn.x + zm.x + zp.x + fv.x) * SIXTH;
    o.y = (C.x + C.z + up.y + dn.y + zm.y + zp.y + fv.y) * SIXTH;
    o.z = (C.y + C.w + up.z + dn.z + zm.z + zp.z + fv.z) * SIXTH;
    o.w = (C.z + rgt + up.w + dn.w + zm.w + zp.w + fv.w) * SIXTH;

    const size_t oi = ((size_t)z * NI + y) * NI + gx0;
    *reinterpret_cast<float4*>(&out[oi]) = o;
    *reinterpret_cast<float4*>(&g[oi])  = fv;
}

// Final single sweep, float4, using g.
__global__ void step_last_v(const float4* __restrict__ u4,
                            const float4* __restrict__ g4,
                            float4* __restrict__ out4) {
    const int tx = threadIdx.x;                    // 0..63
    const int y  = blockIdx.y * 4 + threadIdx.y;
    const int z  = blockIdx.z;
    const int rowq   = NI / 4;
    const int planeq = NI * rowq;
    const int r = z * planeq + y * rowq + tx;

    const float4 v = u4[r];
    float left  = __shfl_up(v.w, 1);
    float right = __shfl_down(v.x, 1);
    if (tx == 0)  left  = 0.0f;
    if (tx == 63) right = 0.0f;

    float4 nb;
    nb.x = left + v.y;
    nb.y = v.x  + v.z;
    nb.z = v.y  + v.w;
    nb.w = v.z  + right;

    if (y > 0)      { float4 b = u4[r - rowq];   nb.x += b.x; nb.y += b.y; nb.z += b.z; nb.w += b.w; }
    if (y < NI - 1) { float4 b = u4[r + rowq];   nb.x += b.x; nb.y += b.y; nb.z += b.z; nb.w += b.w; }
    if (z > 0)      { float4 b = u4[r - planeq]; nb.x += b.x; nb.y += b.y; nb.z += b.z; nb.w += b.w; }
    if (z < NI - 1) { float4 b = u4[r + planeq]; nb.x += b.x; nb.y += b.y; nb.z += b.z; nb.w += b.w; }

    const float4 gv = g4[r];
    float4 o;
    o.x = (nb.x + gv.x) * SIXTH;
    o.y = (nb.y + gv.y) * SIXTH;
    o.z = (nb.z + gv.z) * SIXTH;
    o.w = (nb.w + gv.w) * SIXTH;
    out4[r] = o;
}

// Fused double sweep out = J(J(u)), float4 2.5D pipeline, prefetched globals.
// Per iter t: A writes reg->su[t+2], issues loads for next iter (u[t+3],
// g for W(t+1), g for O(t+1)); bar; W computes sw[t+1] from su[t..t+2]+gw;
// bar; O stores out[t] from sw[t-1..t+1]+go.
__global__ __launch_bounds__(512, 8)
void step_fused2p(const float* __restrict__ u,
                  const float* __restrict__ g,
                  float* __restrict__ out) {
    __shared__ float4 su[3][SU_ROWS][SU_P];
    __shared__ float4 sw[3][SW_ROWS][SW_P];

    const int tid = threadIdx.x;

    // XCD-contiguous tile remap: grid 8x8x16 = 1024 = 8 XCDs x 128 chunks.
    const int lid = blockIdx.x + (blockIdx.y << 3) + (blockIdx.z << 6);
    const int swz = (lid & 7) * 128 + (lid >> 3);
    const int x0 = (swz & 7) * TX;
    const int y0 = ((swz >> 3) & 7) * TY;
    const int z0 = (swz >> 6) * CZ;
    const int zend = z0 + CZ;
    const int plq = NI * NI;

    // ---- loop-invariant per-thread mappings ----
    // A/L: 360 threads, one f4 chunk each
    const int lr = tid / SU_Q, lc = tid - lr * SU_Q;
    const bool lact = tid < SU_ROWS * SU_Q;
    const int lgy = y0 - 2 + lr, lgx0 = x0 - 4 + 4 * lc;
    const bool lxy = lact && lgy >= 0 && lgy < NI && lgx0 >= 0 && lgx0 < NI;
    const int lbase = lgy * NI + lgx0;

    // W: 340 threads
    const int wr = tid / SW_Q, wc = tid - wr * SW_Q;
    const bool wact = tid < SW_ROWS * SW_Q;
    const int wgy = y0 - 1 + wr, wgx0 = x0 - 4 + 4 * wc;
    const bool wxy = wact && wgy >= 0 && wgy < NI && wgx0 >= 0 && wgx0 < NI;
    const int wcm = (wc > 0) ? wc - 1 : 0;              // clamped; garbage comps unused
    const int wcp = (wc < SU_Q - 1) ? wc + 1 : SU_Q - 1;
    const int wbase = wgy * NI + wgx0;

    // O: 256 threads
    const int orr = tid >> 3, oc = tid & 7;
    const bool oact = tid < 256;
    const int ogy = y0 + orr, ogx0 = x0 + 4 * oc;
    const int obase = ogy * NI + ogx0;

    float4 ru = zero4(), gwn = zero4(), gon = zero4();
    {   // pre-issue u plane z0-2 (written at first A)
        const int pl = z0 - 2;
        if (lxy && pl >= 0)
            ru = *reinterpret_cast<const float4*>(&u[(size_t)pl * plq + lbase]);
    }

    for (int t = z0 - 4; t < zend; ++t) {
        // ---- A: write su plane t+2; issue prefetches for iter t+1 ----
        if (lact) su[(t + 5) % 3][lr][lc] = ru;
        ru = zero4();
        {   const int pl = t + 3;
            if (t < zend - 1 && pl >= 0 && pl < NI && lxy)
                ru = *reinterpret_cast<const float4*>(&u[(size_t)pl * plq + lbase]);
        }
        const float4 gw = gwn;   // g[t+1], for W this iter
        {   const int p2 = t + 2;
            if (t >= z0 - 3 && t < zend - 1 && p2 >= 0 && p2 < NI && wxy)
                gwn = *reinterpret_cast<const float4*>(&g[(size_t)p2 * plq + wbase]);
        }
        const float4 go = gon;   // g[t], for O this iter
        {   const int p1 = t + 1;
            if (p1 >= z0 && p1 < zend && oact)
                gon = *reinterpret_cast<const float4*>(&g[(size_t)p1 * plq + obase]);
        }
        __syncthreads();
        // ---- W: compute sw plane pw = t+1 from su[t..t+2] + gw ----
        if (wact && t >= z0 - 2) {
            const int pw = t + 1;
            float4 wv = zero4();
            if (wxy && pw >= 0 && pw < NI) {
                const int sc = (pw + 3) % 3, sm = (pw + 2) % 3, sp = (pw + 4) % 3;
                const float4 cc  = su[sc][wr + 1][wc];
                const float4 cp  = su[sc][wr + 1][wcm];
                const float4 cn  = su[sc][wr + 1][wcp];
                const float4 uy  = su[sc][wr][wc];
                const float4 dy  = su[sc][wr + 2][wc];
                const float4 zmv = su[sm][wr + 1][wc];
                const float4 zpv = su[sp][wr + 1][wc];
                wv.x = (cp.w + cc.y + uy.x + dy.x + zmv.x + zpv.x + gw.x) * SIXTH;
                wv.y = (cc.x + cc.z + uy.y + dy.y + zmv.y + zpv.y + gw.y) * SIXTH;
                wv.z = (cc.y + cc.w + uy.z + dy.z + zmv.z + zpv.z + gw.z) * SIXTH;
                wv.w = (cc.z + cn.x + uy.w + dy.w + zmv.w + zpv.w + gw.w) * SIXTH;
            }
            sw[(pw + 3) % 3][wr][wc] = wv;
        }
        __syncthreads();
        // ---- O: out plane t from sw[t-1..t+1] + go ----
        if (oact && t >= z0) {
            const int sc = (t + 3) % 3, sm = (t + 2) % 3, sp = (t + 4) % 3;
            const float4 cc  = sw[sc][orr + 1][oc + 1];
            const float4 cp  = sw[sc][orr + 1][oc];
            const float4 cn  = sw[sc][orr + 1][oc + 2];
            const float4 uy  = sw[sc][orr][oc + 1];
            const float4 dy  = sw[sc][orr + 2][oc + 1];
            const float4 zmv = sw[sm][orr + 1][oc + 1];
            const float4 zpv = sw[sp][orr + 1][oc + 1];
            float4 ov;
            ov.x = (cp.w + cc.y + uy.x + dy.x + zmv.x + zpv.x + go.x) * SIXTH;
            ov.y = (cc.x + cc.z + uy.y + dy.y + zmv.y + zpv.y + go.y) * SIXTH;
            ov.z = (cc.y + cc.w + uy.z + dy.z + zmv.z + zpv.z + go.z) * SIXTH;
            ov.w = (cc.z + cn.x + uy.w + dy.w + zmv.w + zpv.w + go.w) * SIXTH;
            *reinterpret_cast<float4*>(&out[(size_t)t * plq + obase]) = ov;
        }
        // no barrier needed here: next A writes su slot already retired at bar2,
        // and touches neither sw nor anything O reads.
    }
}

extern "C" void kernel_launch(void* const* d_in, const int* in_sizes, int n_in,
                              void* d_out, int out_size, void* d_ws, size_t ws_size,
                              hipStream_t stream) {
    const float* pre = (const float*)d_in[0];
    const float* f   = (const float*)d_in[1];
    float* out = (float*)d_out;
    float* buf = (float*)d_ws;                          // 64 MiB ping-pong
    const size_t nInt = (size_t)NI * NI * NI;
    float* g = buf + nInt;                              // 64 MiB, g = h^2*f

    // 20 sweeps: step_first (1) + 9 fused (18) + 1 single.
    step_first_v<<<dim3(1, NI / 4, NI), dim3(64, 4, 1), 0, stream>>>(pre, f, out, g);

    float* cur = out;
    float* nxt = buf;
    dim3 fg(NI / TX, NI / TY, NI / CZ);                 // 8x8x16 = 1024 blocks
    for (int i = 0; i < 9; ++i) {
        step_fused2p<<<fg, dim3(512, 1, 1), 0, stream>>>(cur, g, nxt);
        float* tmp = cur; cur = nxt; nxt = tmp;
    }
    // cur == buf after 9 swaps; final single sweep buf -> out.
    step_last_v<<<dim3(1, NI / 4, NI), dim3(64, 4, 1), 0, stream>>>(
        (const float4*)cur, (const float4*)g, (float4*)out);
}